// Round 6
// baseline (312.571 us; speedup 1.0000x reference)
//
#include <hip/hip_runtime.h>

#define NBINS 256
#define NCOPY 32
#define GRID1 1024
#define GRID2 1024
#define TPB   512   // 8 waves/block; 4 blocks/CU (32KB LDS) -> 32 waves/CU = 100%

// Order-preserving float->uint encoding (monotone increasing).
__device__ __forceinline__ unsigned enc_f(float f) {
    unsigned u = __float_as_uint(f);
    return (u & 0x80000000u) ? ~u : (u | 0x80000000u);
}
__device__ __forceinline__ float dec_f(unsigned u) {
    unsigned v = (u & 0x80000000u) ? (u & 0x7FFFFFFFu) : ~u;
    return __uint_as_float(v);
}

// ws layout (uint32):
//   [0 .. GRID1)              per-block min (enc), plain-stored every call
//   [GRID1 .. 2*GRID1)        per-block max (enc)
//   [2*GRID1 .. 2*GRID1+256)  global hist bins (zeroed by pass1 block 0)
//   [2*GRID1+256]             completion counter (zeroed by pass1 block 0)

__device__ __forceinline__ void minmax16(const float4& a, const float4& b,
                                         const float4& c, const float4& d,
                                         float& lmin, float& lmax) {
    float mn = fminf(fminf(fminf(a.x, a.y), fminf(a.z, a.w)),
                     fminf(fminf(b.x, b.y), fminf(b.z, b.w)));
    mn = fminf(mn, fminf(fminf(fminf(c.x, c.y), fminf(c.z, c.w)),
                         fminf(fminf(d.x, d.y), fminf(d.z, d.w))));
    float mx = fmaxf(fmaxf(fmaxf(a.x, a.y), fmaxf(a.z, a.w)),
                     fmaxf(fmaxf(b.x, b.y), fmaxf(b.z, b.w)));
    mx = fmaxf(mx, fmaxf(fmaxf(fmaxf(c.x, c.y), fmaxf(c.z, c.w)),
                         fmaxf(fmaxf(d.x, d.y), fmaxf(d.z, d.w))));
    lmin = fminf(lmin, mn);
    lmax = fmaxf(lmax, mx);
}

__global__ __launch_bounds__(TPB) void hrt_pass1(
        const float4* __restrict__ in4, long n4,
        const float* __restrict__ in, long n,
        unsigned* __restrict__ pmin, unsigned* __restrict__ pmax,
        unsigned* __restrict__ hist, unsigned* __restrict__ cnt) {
    const int tid = threadIdx.x;
    const int bid = blockIdx.x;

    // block 0 re-inits bins + counter for this call (LLC-homed atomics,
    // published to pass2 by the kernel boundary)
    if (bid == 0) {
        for (int j = tid; j < NBINS; j += TPB) atomicExch(&hist[j], 0u);
        if (tid == 0) atomicExch(cnt, 0u);
    }

    float lmin = INFINITY, lmax = -INFINITY;
    const long stride = (long)GRID1 * TPB;
    long i = (long)bid * TPB + tid;
    for (; i + 3 * stride < n4; i += 4 * stride) {
        float4 a = in4[i];
        float4 b = in4[i + stride];
        float4 c = in4[i + 2 * stride];
        float4 d = in4[i + 3 * stride];
        minmax16(a, b, c, d, lmin, lmax);
    }
    for (; i < n4; i += stride) {
        float4 a = in4[i];
        lmin = fminf(lmin, fminf(fminf(a.x, a.y), fminf(a.z, a.w)));
        lmax = fmaxf(lmax, fmaxf(fmaxf(a.x, a.y), fmaxf(a.z, a.w)));
    }
    for (long j = n4 * 4 + (long)bid * TPB + tid; j < n; j += stride) {
        float v = in[j];
        lmin = fminf(lmin, v);
        lmax = fmaxf(lmax, v);
    }

    unsigned emin = enc_f(lmin), emax = enc_f(lmax);
    #pragma unroll
    for (int off = 32; off > 0; off >>= 1) {
        emin = min(emin, (unsigned)__shfl_down((int)emin, off));
        emax = max(emax, (unsigned)__shfl_down((int)emax, off));
    }
    __shared__ unsigned sred[16];
    const int wave = tid >> 6, lane = tid & 63;
    if (lane == 0) { sred[wave] = emin; sred[8 + wave] = emax; }
    __syncthreads();
    if (tid == 0) {
        unsigned m0 = sred[0], m1 = sred[8];
        #pragma unroll
        for (int w = 1; w < TPB / 64; ++w) {
            m0 = min(m0, sred[w]);
            m1 = max(m1, sred[8 + w]);
        }
        pmin[bid] = m0;   // plain stores; kernel boundary publishes them
        pmax[bid] = m1;
    }
}

__global__ __launch_bounds__(TPB) void hrt_pass2(
        const float4* __restrict__ in4, long n4,
        const float* __restrict__ in, long n,
        const unsigned* __restrict__ pmin, const unsigned* __restrict__ pmax,
        unsigned* __restrict__ hist, unsigned* __restrict__ cnt,
        float* __restrict__ out) {
    __shared__ unsigned lh[NBINS * NCOPY];
    __shared__ unsigned sred[16];
    __shared__ unsigned sbc[2];
    __shared__ unsigned sIsLast;

    const int tid = threadIdx.x;
    const int bid = blockIdx.x;
    const int wave = tid >> 6, lane = tid & 63;

    for (int j = tid; j < NBINS * NCOPY; j += TPB) lh[j] = 0u;

    // reduce GRID1 partials per array: 1024 words = 512 threads x uint2
    {
        uint2 a = ((const uint2*)pmin)[tid];
        uint2 b = ((const uint2*)pmax)[tid];
        unsigned gmin = min(a.x, a.y);
        unsigned gmax = max(b.x, b.y);
        #pragma unroll
        for (int off = 32; off > 0; off >>= 1) {
            gmin = min(gmin, (unsigned)__shfl_down((int)gmin, off));
            gmax = max(gmax, (unsigned)__shfl_down((int)gmax, off));
        }
        if (lane == 0) { sred[wave] = gmin; sred[8 + wave] = gmax; }
    }
    __syncthreads();
    if (tid == 0) {
        unsigned m0 = sred[0], m1 = sred[8];
        #pragma unroll
        for (int w = 1; w < TPB / 64; ++w) {
            m0 = min(m0, sred[w]);
            m1 = max(m1, sred[8 + w]);
        }
        sbc[0] = m0;
        sbc[1] = m1;
    }
    __syncthreads();
    const float tmin = dec_f(sbc[0]);
    const float tmax = dec_f(sbc[1]);
    const float scale = (float)NBINS / (tmax - tmin);
    const float bias = -tmin * scale;
    const int copy = tid & (NCOPY - 1);

    #define HIST1(v)  do { \
        int ix = (int)fmaf((v), scale, bias); \
        ix = ix < 0 ? 0 : (ix > NBINS - 1 ? NBINS - 1 : ix); \
        atomicAdd(&lh[ix * NCOPY + copy], 1u); } while (0)
    #define HIST4(q)  do { HIST1((q).x); HIST1((q).y); HIST1((q).z); HIST1((q).w); } while (0)

    {
        const long stride = (long)GRID2 * TPB;
        long i = (long)bid * TPB + tid;
        for (; i + 3 * stride < n4; i += 4 * stride) {
            float4 a = in4[i];
            float4 b = in4[i + stride];
            float4 c = in4[i + 2 * stride];
            float4 d = in4[i + 3 * stride];
            HIST4(a); HIST4(b); HIST4(c); HIST4(d);
        }
        for (; i < n4; i += stride) {
            float4 a = in4[i];
            HIST4(a);
        }
        for (long j = n4 * 4 + (long)bid * TPB + tid; j < n; j += stride)
            HIST1(in[j]);
    }
    __syncthreads();

    // merge LDS hist into global bins (one atomic per nonzero bin)
    if (tid < NBINS) {
        unsigned t = 0;
        #pragma unroll
        for (int c2 = 0; c2 < NCOPY; ++c2) {
            int cc = (c2 + lane) & (NCOPY - 1);
            t += lh[tid * NCOPY + cc];
        }
        if (t) atomicAdd(&hist[tid], t);
    }

    // last block finalizes
    __threadfence();
    if (tid == 0) sIsLast = (atomicAdd(cnt, 1u) == GRID2 - 1) ? 1u : 0u;
    __syncthreads();
    if (sIsLast) {
        float* hf = (float*)lh;  // reuse LDS
        if (tid < NBINS) hf[tid] = (float)atomicAdd(&hist[tid], 0u);
        __syncthreads();
        if (tid == 0) {
            float total = 0.0f;
            for (int j = 0; j < NBINS; ++j) total += hf[j];
            float tl = total * (1.0f - 0.99f) / 2.0f;
            float tu = total * (1.0f + 0.99f) / 2.0f;
            int lower = -1, upper = -1;
            float cum = 0.0f;
            for (int j = 0; j < NBINS; ++j) {
                cum += hf[j];
                if (lower < 0 && cum > tl) lower = j;
                if (upper < 0 && cum > tu) upper = j;
            }
            if (lower < 0) lower = 0;
            if (upper < 0) upper = 0;
            float step = (tmax - tmin) / (float)NBINS;
            out[0] = tmin + step * (float)lower;
            out[1] = tmin + step * (float)upper;
        }
    }
    #undef HIST1
    #undef HIST4
}

extern "C" void kernel_launch(void* const* d_in, const int* in_sizes, int n_in,
                              void* d_out, int out_size, void* d_ws, size_t ws_size,
                              hipStream_t stream) {
    const float* in = (const float*)d_in[0];
    long n = (long)in_sizes[0];
    long n4 = n / 4;
    unsigned* ws = (unsigned*)d_ws;
    float* out = (float*)d_out;

    unsigned* pmin = ws;
    unsigned* pmax = ws + GRID1;
    unsigned* hist = ws + 2 * GRID1;
    unsigned* cnt  = ws + 2 * GRID1 + NBINS;

    hrt_pass1<<<GRID1, TPB, 0, stream>>>((const float4*)in, n4, in, n,
                                         pmin, pmax, hist, cnt);
    hrt_pass2<<<GRID2, TPB, 0, stream>>>((const float4*)in, n4, in, n,
                                         pmin, pmax, hist, cnt, out);
}

// Round 7
// 298.244 us; speedup vs baseline: 1.0480x; 1.0480x over previous
//
#include <hip/hip_runtime.h>

#define NBINS 256
#define NCOPY 32
#define GRID1 2048
#define GRID2 2048
#define TPB   256

// Order-preserving float->uint encoding (monotone increasing).
__device__ __forceinline__ unsigned enc_f(float f) {
    unsigned u = __float_as_uint(f);
    return (u & 0x80000000u) ? ~u : (u | 0x80000000u);
}
__device__ __forceinline__ float dec_f(unsigned u) {
    unsigned v = (u & 0x80000000u) ? (u & 0x7FFFFFFFu) : ~u;
    return __uint_as_float(v);
}

// ws layout (uint32):
//   [0 .. GRID1)              per-block min (enc), plain-stored every call
//   [GRID1 .. 2*GRID1)        per-block max (enc)
//   [2*GRID1 .. 2*GRID1+256)  global hist bins (zeroed by pass1 block 0)
//   [2*GRID1+256]             completion counter (zeroed by pass1 block 0)

__device__ __forceinline__ void minmax16(const float4& a, const float4& b,
                                         const float4& c, const float4& d,
                                         float& lmin, float& lmax) {
    float mn = fminf(fminf(fminf(a.x, a.y), fminf(a.z, a.w)),
                     fminf(fminf(b.x, b.y), fminf(b.z, b.w)));
    mn = fminf(mn, fminf(fminf(fminf(c.x, c.y), fminf(c.z, c.w)),
                         fminf(fminf(d.x, d.y), fminf(d.z, d.w))));
    float mx = fmaxf(fmaxf(fmaxf(a.x, a.y), fmaxf(a.z, a.w)),
                     fmaxf(fmaxf(b.x, b.y), fmaxf(b.z, b.w)));
    mx = fmaxf(mx, fmaxf(fmaxf(fmaxf(c.x, c.y), fmaxf(c.z, c.w)),
                         fmaxf(fmaxf(d.x, d.y), fmaxf(d.z, d.w))));
    lmin = fminf(lmin, mn);
    lmax = fmaxf(lmax, mx);
}

__global__ __launch_bounds__(TPB) void hrt_pass1(
        const float4* __restrict__ in4, long n4,
        const float* __restrict__ in, long n,
        unsigned* __restrict__ pmin, unsigned* __restrict__ pmax,
        unsigned* __restrict__ hist, unsigned* __restrict__ cnt) {
    const int tid = threadIdx.x;
    const int bid = blockIdx.x;

    // block 0 re-inits bins + counter for this call (LLC-homed atomics,
    // published to pass2 by the kernel boundary)
    if (bid == 0) {
        for (int j = tid; j < NBINS; j += TPB) atomicExch(&hist[j], 0u);
        if (tid == 0) atomicExch(cnt, 0u);
    }

    float lmin = INFINITY, lmax = -INFINITY;
    const long stride = (long)GRID1 * TPB;
    long i = (long)bid * TPB + tid;
    for (; i + 3 * stride < n4; i += 4 * stride) {
        float4 a = in4[i];
        float4 b = in4[i + stride];
        float4 c = in4[i + 2 * stride];
        float4 d = in4[i + 3 * stride];
        minmax16(a, b, c, d, lmin, lmax);
    }
    for (; i < n4; i += stride) {
        float4 a = in4[i];
        lmin = fminf(lmin, fminf(fminf(a.x, a.y), fminf(a.z, a.w)));
        lmax = fmaxf(lmax, fmaxf(fmaxf(a.x, a.y), fmaxf(a.z, a.w)));
    }
    for (long j = n4 * 4 + (long)bid * TPB + tid; j < n; j += stride) {
        float v = in[j];
        lmin = fminf(lmin, v);
        lmax = fmaxf(lmax, v);
    }

    unsigned emin = enc_f(lmin), emax = enc_f(lmax);
    #pragma unroll
    for (int off = 32; off > 0; off >>= 1) {
        emin = min(emin, (unsigned)__shfl_down((int)emin, off));
        emax = max(emax, (unsigned)__shfl_down((int)emax, off));
    }
    __shared__ unsigned sred[8];
    const int wave = tid >> 6, lane = tid & 63;
    if (lane == 0) { sred[wave] = emin; sred[4 + wave] = emax; }
    __syncthreads();
    if (tid == 0) {
        unsigned m0 = min(min(sred[0], sred[1]), min(sred[2], sred[3]));
        unsigned m1 = max(max(sred[4], sred[5]), max(sred[6], sred[7]));
        pmin[bid] = m0;   // plain stores; kernel boundary publishes them
        pmax[bid] = m1;
    }
}

__global__ __launch_bounds__(TPB) void hrt_pass2(
        const float4* __restrict__ in4, long n4,
        const float* __restrict__ in, long n,
        const unsigned* __restrict__ pmin, const unsigned* __restrict__ pmax,
        unsigned* __restrict__ hist, unsigned* __restrict__ cnt,
        float* __restrict__ out) {
    __shared__ unsigned lh[NBINS * NCOPY];
    __shared__ unsigned sred[8];
    __shared__ unsigned sbc[2];
    __shared__ unsigned sIsLast;

    const int tid = threadIdx.x;
    const int bid = blockIdx.x;
    const int wave = tid >> 6, lane = tid & 63;

    for (int j = tid; j < NBINS * NCOPY; j += TPB) lh[j] = 0u;

    // reduce GRID1 partials per array: 2048 words = 256 threads x uint4 x 2
    {
        const uint4* p4min = (const uint4*)pmin;
        const uint4* p4max = (const uint4*)pmax;
        uint4 a0 = p4min[tid], a1 = p4min[tid + TPB];
        uint4 b0 = p4max[tid], b1 = p4max[tid + TPB];
        unsigned gmin = min(min(min(a0.x, a0.y), min(a0.z, a0.w)),
                            min(min(a1.x, a1.y), min(a1.z, a1.w)));
        unsigned gmax = max(max(max(b0.x, b0.y), max(b0.z, b0.w)),
                            max(max(b1.x, b1.y), max(b1.z, b1.w)));
        #pragma unroll
        for (int off = 32; off > 0; off >>= 1) {
            gmin = min(gmin, (unsigned)__shfl_down((int)gmin, off));
            gmax = max(gmax, (unsigned)__shfl_down((int)gmax, off));
        }
        if (lane == 0) { sred[wave] = gmin; sred[4 + wave] = gmax; }
    }
    __syncthreads();
    if (tid == 0) {
        sbc[0] = min(min(sred[0], sred[1]), min(sred[2], sred[3]));
        sbc[1] = max(max(sred[4], sred[5]), max(sred[6], sred[7]));
    }
    __syncthreads();
    const float tmin = dec_f(sbc[0]);
    const float tmax = dec_f(sbc[1]);
    const float scale = (float)NBINS / (tmax - tmin);
    const int copy = tid & (NCOPY - 1);

    // round-2-faithful inner loop: simple grid-stride, load -> 4 atomics
    {
        const long stride = (long)GRID2 * TPB;
        long gtid = (long)bid * TPB + tid;
        for (long i = gtid; i < n4; i += stride) {
            float4 v = in4[i];
            float c[4] = {v.x, v.y, v.z, v.w};
            #pragma unroll
            for (int k = 0; k < 4; ++k) {
                int idx = (int)((c[k] - tmin) * scale);
                idx = idx < 0 ? 0 : (idx > NBINS - 1 ? NBINS - 1 : idx);
                atomicAdd(&lh[idx * NCOPY + copy], 1u);
            }
        }
        for (long j = n4 * 4 + gtid; j < n; j += stride) {
            int idx = (int)((in[j] - tmin) * scale);
            idx = idx < 0 ? 0 : (idx > NBINS - 1 ? NBINS - 1 : idx);
            atomicAdd(&lh[idx * NCOPY + copy], 1u);
        }
    }
    __syncthreads();

    // merge LDS hist into global bins (one atomic per nonzero bin)
    for (int b = tid; b < NBINS; b += TPB) {
        unsigned t = 0;
        #pragma unroll
        for (int c2 = 0; c2 < NCOPY; ++c2) {
            int cc = (c2 + lane) & (NCOPY - 1);
            t += lh[b * NCOPY + cc];
        }
        if (t) atomicAdd(&hist[b], t);
    }

    // last block finalizes
    __threadfence();
    if (tid == 0) sIsLast = (atomicAdd(cnt, 1u) == GRID2 - 1) ? 1u : 0u;
    __syncthreads();
    if (sIsLast) {
        float* hf = (float*)lh;  // reuse LDS
        if (tid < NBINS) hf[tid] = (float)atomicAdd(&hist[tid], 0u);
        __syncthreads();
        if (tid == 0) {
            float total = 0.0f;
            for (int j = 0; j < NBINS; ++j) total += hf[j];
            float tl = total * (1.0f - 0.99f) / 2.0f;
            float tu = total * (1.0f + 0.99f) / 2.0f;
            int lower = -1, upper = -1;
            float cum = 0.0f;
            for (int j = 0; j < NBINS; ++j) {
                cum += hf[j];
                if (lower < 0 && cum > tl) lower = j;
                if (upper < 0 && cum > tu) upper = j;
            }
            if (lower < 0) lower = 0;
            if (upper < 0) upper = 0;
            float step = (tmax - tmin) / (float)NBINS;
            out[0] = tmin + step * (float)lower;
            out[1] = tmin + step * (float)upper;
        }
    }
}

extern "C" void kernel_launch(void* const* d_in, const int* in_sizes, int n_in,
                              void* d_out, int out_size, void* d_ws, size_t ws_size,
                              hipStream_t stream) {
    const float* in = (const float*)d_in[0];
    long n = (long)in_sizes[0];
    long n4 = n / 4;
    unsigned* ws = (unsigned*)d_ws;
    float* out = (float*)d_out;

    unsigned* pmin = ws;
    unsigned* pmax = ws + GRID1;
    unsigned* hist = ws + 2 * GRID1;
    unsigned* cnt  = ws + 2 * GRID1 + NBINS;

    hrt_pass1<<<GRID1, TPB, 0, stream>>>((const float4*)in, n4, in, n,
                                         pmin, pmax, hist, cnt);
    hrt_pass2<<<GRID2, TPB, 0, stream>>>((const float4*)in, n4, in, n,
                                         pmin, pmax, hist, cnt, out);
}

// Round 8
// 132.359 us; speedup vs baseline: 2.3615x; 2.2533x over previous
//
#include <hip/hip_runtime.h>

#define NBINS 256
#define NCOPY 32
#define GRID1 2048
#define GRID2 2048
#define TPB   256

// Order-preserving float->uint encoding (monotone increasing).
__device__ __forceinline__ unsigned enc_f(float f) {
    unsigned u = __float_as_uint(f);
    return (u & 0x80000000u) ? ~u : (u | 0x80000000u);
}
__device__ __forceinline__ float dec_f(unsigned u) {
    unsigned v = (u & 0x80000000u) ? (u & 0x7FFFFFFFu) : ~u;
    return __uint_as_float(v);
}

// ws layout (uint32):
//   [0 .. GRID1)                 per-block min (enc), plain-stored every call
//   [GRID1 .. 2*GRID1)           per-block max (enc)
//   [2*GRID1 .. 2*GRID1+NBINS)   global hist bins (zeroed by pass1 block 0)
//   [2*GRID1+NBINS .. +2]        encoded global {min,max} (written by hrt_mid)

__device__ __forceinline__ void minmax16(const float4& a, const float4& b,
                                         const float4& c, const float4& d,
                                         float& lmin, float& lmax) {
    float mn = fminf(fminf(fminf(a.x, a.y), fminf(a.z, a.w)),
                     fminf(fminf(b.x, b.y), fminf(b.z, b.w)));
    mn = fminf(mn, fminf(fminf(fminf(c.x, c.y), fminf(c.z, c.w)),
                         fminf(fminf(d.x, d.y), fminf(d.z, d.w))));
    float mx = fmaxf(fmaxf(fmaxf(a.x, a.y), fmaxf(a.z, a.w)),
                     fmaxf(fmaxf(b.x, b.y), fmaxf(b.z, b.w)));
    mx = fmaxf(mx, fmaxf(fmaxf(fmaxf(c.x, c.y), fmaxf(c.z, c.w)),
                         fmaxf(fmaxf(d.x, d.y), fmaxf(d.z, d.w))));
    lmin = fminf(lmin, mn);
    lmax = fmaxf(lmax, mx);
}

__global__ __launch_bounds__(TPB) void hrt_pass1(
        const float4* __restrict__ in4, long n4,
        const float* __restrict__ in, long n,
        unsigned* __restrict__ pmin, unsigned* __restrict__ pmax,
        unsigned* __restrict__ hist) {
    const int tid = threadIdx.x;
    const int bid = blockIdx.x;

    // block 0 re-inits bins for this call (LLC-homed atomics; ordered vs
    // pass2's atomicAdds by the kernel boundary)
    if (bid == 0) {
        for (int j = tid; j < NBINS; j += TPB) atomicExch(&hist[j], 0u);
    }

    float lmin = INFINITY, lmax = -INFINITY;
    const long stride = (long)GRID1 * TPB;
    long i = (long)bid * TPB + tid;
    for (; i + 3 * stride < n4; i += 4 * stride) {
        float4 a = in4[i];
        float4 b = in4[i + stride];
        float4 c = in4[i + 2 * stride];
        float4 d = in4[i + 3 * stride];
        minmax16(a, b, c, d, lmin, lmax);
    }
    for (; i < n4; i += stride) {
        float4 a = in4[i];
        lmin = fminf(lmin, fminf(fminf(a.x, a.y), fminf(a.z, a.w)));
        lmax = fmaxf(lmax, fmaxf(fmaxf(a.x, a.y), fmaxf(a.z, a.w)));
    }
    for (long j = n4 * 4 + (long)bid * TPB + tid; j < n; j += stride) {
        float v = in[j];
        lmin = fminf(lmin, v);
        lmax = fmaxf(lmax, v);
    }

    unsigned emin = enc_f(lmin), emax = enc_f(lmax);
    #pragma unroll
    for (int off = 32; off > 0; off >>= 1) {
        emin = min(emin, (unsigned)__shfl_down((int)emin, off));
        emax = max(emax, (unsigned)__shfl_down((int)emax, off));
    }
    __shared__ unsigned sred[8];
    const int wave = tid >> 6, lane = tid & 63;
    if (lane == 0) { sred[wave] = emin; sred[4 + wave] = emax; }
    __syncthreads();
    if (tid == 0) {
        unsigned m0 = min(min(sred[0], sred[1]), min(sred[2], sred[3]));
        unsigned m1 = max(max(sred[4], sred[5]), max(sred[6], sred[7]));
        pmin[bid] = m0;   // plain stores; kernel boundary publishes them
        pmax[bid] = m1;
    }
}

// Single block: reduce the 2*GRID1 partials once; publish enc'd tmin/tmax.
__global__ void hrt_mid(const unsigned* __restrict__ pmin,
                        const unsigned* __restrict__ pmax,
                        unsigned* __restrict__ mm) {
    __shared__ unsigned sred[16];
    const int tid = threadIdx.x;           // 512 threads
    const int wave = tid >> 6, lane = tid & 63;
    uint4 a = ((const uint4*)pmin)[tid];   // 512 x 4 = 2048 words
    uint4 b = ((const uint4*)pmax)[tid];
    unsigned gmin = min(min(a.x, a.y), min(a.z, a.w));
    unsigned gmax = max(max(b.x, b.y), max(b.z, b.w));
    #pragma unroll
    for (int off = 32; off > 0; off >>= 1) {
        gmin = min(gmin, (unsigned)__shfl_down((int)gmin, off));
        gmax = max(gmax, (unsigned)__shfl_down((int)gmax, off));
    }
    if (lane == 0) { sred[wave] = gmin; sred[8 + wave] = gmax; }
    __syncthreads();
    if (tid == 0) {
        unsigned m0 = sred[0], m1 = sred[8];
        #pragma unroll
        for (int w = 1; w < 8; ++w) {
            m0 = min(m0, sred[w]);
            m1 = max(m1, sred[8 + w]);
        }
        mm[0] = m0;   // plain stores; kernel boundary publishes them
        mm[1] = m1;
    }
}

// Round-2-faithful histogram kernel: no __launch_bounds__, no fences, no
// counters; reads tmin/tmax as two scalar words.
__global__ void hrt_hist(const float4* __restrict__ in4, long n4,
                         const float* __restrict__ in, long n,
                         const unsigned* __restrict__ mm,
                         unsigned* __restrict__ hist) {
    __shared__ unsigned lh[NBINS * NCOPY];
    for (int i = threadIdx.x; i < NBINS * NCOPY; i += blockDim.x) lh[i] = 0u;
    __syncthreads();
    float tmin = dec_f(mm[0]);
    float tmax = dec_f(mm[1]);
    float scale = (float)NBINS / (tmax - tmin);
    int copy = threadIdx.x & (NCOPY - 1);
    long tid = (long)blockIdx.x * blockDim.x + threadIdx.x;
    long stride = (long)gridDim.x * blockDim.x;
    for (long i = tid; i < n4; i += stride) {
        float4 v = in4[i];
        float c[4] = {v.x, v.y, v.z, v.w};
        #pragma unroll
        for (int k = 0; k < 4; ++k) {
            int idx = (int)((c[k] - tmin) * scale);
            idx = idx < 0 ? 0 : (idx > NBINS - 1 ? NBINS - 1 : idx);
            atomicAdd(&lh[idx * NCOPY + copy], 1u);
        }
    }
    for (long i = n4 * 4 + tid; i < n; i += stride) {
        int idx = (int)((in[i] - tmin) * scale);
        idx = idx < 0 ? 0 : (idx > NBINS - 1 ? NBINS - 1 : idx);
        atomicAdd(&lh[idx * NCOPY + copy], 1u);
    }
    __syncthreads();
    int lane = threadIdx.x & 63;
    for (int b = threadIdx.x; b < NBINS; b += blockDim.x) {
        unsigned t = 0;
        #pragma unroll
        for (int c = 0; c < NCOPY; ++c) {
            int cc = (c + lane) & (NCOPY - 1);
            t += lh[b * NCOPY + cc];
        }
        if (t) atomicAdd(&hist[b], t);
    }
}

__global__ void hrt_fin(const unsigned* __restrict__ hist,
                        const unsigned* __restrict__ mm,
                        float* __restrict__ out) {
    if (threadIdx.x != 0 || blockIdx.x != 0) return;
    float tmin = dec_f(mm[0]);
    float tmax = dec_f(mm[1]);
    float total = 0.0f;
    for (int i = 0; i < NBINS; ++i) total += (float)hist[i];
    float tl = total * (1.0f - 0.99f) / 2.0f;
    float tu = total * (1.0f + 0.99f) / 2.0f;
    int lower = -1, upper = -1;
    float cum = 0.0f;
    for (int i = 0; i < NBINS; ++i) {
        cum += (float)hist[i];
        if (lower < 0 && cum > tl) lower = i;
        if (upper < 0 && cum > tu) upper = i;
    }
    if (lower < 0) lower = 0;
    if (upper < 0) upper = 0;
    float step = (tmax - tmin) / (float)NBINS;
    out[0] = tmin + step * (float)lower;
    out[1] = tmin + step * (float)upper;
}

extern "C" void kernel_launch(void* const* d_in, const int* in_sizes, int n_in,
                              void* d_out, int out_size, void* d_ws, size_t ws_size,
                              hipStream_t stream) {
    const float* in = (const float*)d_in[0];
    long n = (long)in_sizes[0];
    long n4 = n / 4;
    unsigned* ws = (unsigned*)d_ws;
    float* out = (float*)d_out;

    unsigned* pmin = ws;
    unsigned* pmax = ws + GRID1;
    unsigned* hist = ws + 2 * GRID1;
    unsigned* mm   = ws + 2 * GRID1 + NBINS;

    hrt_pass1<<<GRID1, TPB, 0, stream>>>((const float4*)in, n4, in, n,
                                         pmin, pmax, hist);
    hrt_mid<<<1, 512, 0, stream>>>(pmin, pmax, mm);
    hrt_hist<<<GRID2, TPB, 0, stream>>>((const float4*)in, n4, in, n, mm, hist);
    hrt_fin<<<1, 1, 0, stream>>>(hist, mm, out);
}

// Round 9
// 129.770 us; speedup vs baseline: 2.4087x; 1.0199x over previous
//
#include <hip/hip_runtime.h>

#define NBINS 256
#define NCOPY 32
#define GRID1 2048
#define GRID2 2048
#define TPB   256

// Order-preserving float->uint encoding (monotone increasing).
__device__ __forceinline__ unsigned enc_f(float f) {
    unsigned u = __float_as_uint(f);
    return (u & 0x80000000u) ? ~u : (u | 0x80000000u);
}
__device__ __forceinline__ float dec_f(unsigned u) {
    unsigned v = (u & 0x80000000u) ? (u & 0x7FFFFFFFu) : ~u;
    return __uint_as_float(v);
}

// ws layout (uint32):
//   [0 .. GRID1)                 per-block min (enc), plain-stored every call
//   [GRID1 .. 2*GRID1)           per-block max (enc)
//   [2*GRID1 .. 2*GRID1+NBINS)   global hist bins (zeroed by pass1 block 0)
//   [2*GRID1+NBINS .. +2]        encoded global {min,max} (written by hrt_mid)

__device__ __forceinline__ void minmax16(const float4& a, const float4& b,
                                         const float4& c, const float4& d,
                                         float& lmin, float& lmax) {
    float mn = fminf(fminf(fminf(a.x, a.y), fminf(a.z, a.w)),
                     fminf(fminf(b.x, b.y), fminf(b.z, b.w)));
    mn = fminf(mn, fminf(fminf(fminf(c.x, c.y), fminf(c.z, c.w)),
                         fminf(fminf(d.x, d.y), fminf(d.z, d.w))));
    float mx = fmaxf(fmaxf(fmaxf(a.x, a.y), fmaxf(a.z, a.w)),
                     fmaxf(fmaxf(b.x, b.y), fmaxf(b.z, b.w)));
    mx = fmaxf(mx, fmaxf(fmaxf(fmaxf(c.x, c.y), fmaxf(c.z, c.w)),
                         fmaxf(fmaxf(d.x, d.y), fmaxf(d.z, d.w))));
    lmin = fminf(lmin, mn);
    lmax = fmaxf(lmax, mx);
}

__global__ __launch_bounds__(TPB) void hrt_pass1(
        const float4* __restrict__ in4, long n4,
        const float* __restrict__ in, long n,
        unsigned* __restrict__ pmin, unsigned* __restrict__ pmax,
        unsigned* __restrict__ hist) {
    const int tid = threadIdx.x;
    const int bid = blockIdx.x;

    // block 0 re-inits bins for this call (LLC-homed atomics; ordered vs
    // hist's atomicAdds by the kernel boundary)
    if (bid == 0) {
        for (int j = tid; j < NBINS; j += TPB) atomicExch(&hist[j], 0u);
    }

    float lmin = INFINITY, lmax = -INFINITY;
    const long stride = (long)GRID1 * TPB;
    long i = (long)bid * TPB + tid;
    for (; i + 3 * stride < n4; i += 4 * stride) {
        float4 a = in4[i];
        float4 b = in4[i + stride];
        float4 c = in4[i + 2 * stride];
        float4 d = in4[i + 3 * stride];
        minmax16(a, b, c, d, lmin, lmax);
    }
    for (; i < n4; i += stride) {
        float4 a = in4[i];
        lmin = fminf(lmin, fminf(fminf(a.x, a.y), fminf(a.z, a.w)));
        lmax = fmaxf(lmax, fmaxf(fmaxf(a.x, a.y), fmaxf(a.z, a.w)));
    }
    for (long j = n4 * 4 + (long)bid * TPB + tid; j < n; j += stride) {
        float v = in[j];
        lmin = fminf(lmin, v);
        lmax = fmaxf(lmax, v);
    }

    unsigned emin = enc_f(lmin), emax = enc_f(lmax);
    #pragma unroll
    for (int off = 32; off > 0; off >>= 1) {
        emin = min(emin, (unsigned)__shfl_down((int)emin, off));
        emax = max(emax, (unsigned)__shfl_down((int)emax, off));
    }
    __shared__ unsigned sred[8];
    const int wave = tid >> 6, lane = tid & 63;
    if (lane == 0) { sred[wave] = emin; sred[4 + wave] = emax; }
    __syncthreads();
    if (tid == 0) {
        unsigned m0 = min(min(sred[0], sred[1]), min(sred[2], sred[3]));
        unsigned m1 = max(max(sred[4], sred[5]), max(sred[6], sred[7]));
        pmin[bid] = m0;   // plain stores; kernel boundary publishes them
        pmax[bid] = m1;
    }
}

// Single block: reduce the 2*GRID1 partials once; publish enc'd tmin/tmax.
__global__ void hrt_mid(const unsigned* __restrict__ pmin,
                        const unsigned* __restrict__ pmax,
                        unsigned* __restrict__ mm) {
    __shared__ unsigned sred[16];
    const int tid = threadIdx.x;           // 512 threads
    const int wave = tid >> 6, lane = tid & 63;
    uint4 a = ((const uint4*)pmin)[tid];   // 512 x 4 = 2048 words
    uint4 b = ((const uint4*)pmax)[tid];
    unsigned gmin = min(min(a.x, a.y), min(a.z, a.w));
    unsigned gmax = max(max(b.x, b.y), max(b.z, b.w));
    #pragma unroll
    for (int off = 32; off > 0; off >>= 1) {
        gmin = min(gmin, (unsigned)__shfl_down((int)gmin, off));
        gmax = max(gmax, (unsigned)__shfl_down((int)gmax, off));
    }
    if (lane == 0) { sred[wave] = gmin; sred[8 + wave] = gmax; }
    __syncthreads();
    if (tid == 0) {
        unsigned m0 = sred[0], m1 = sred[8];
        #pragma unroll
        for (int w = 1; w < 8; ++w) {
            m0 = min(m0, sred[w]);
            m1 = max(m1, sred[8 + w]);
        }
        mm[0] = m0;   // plain stores; kernel boundary publishes them
        mm[1] = m1;
    }
}

// Histogram kernel: round-8 structure, but 4 independent loads in flight
// (MLP) before the 16 LDS atomics consume them.
__global__ void hrt_hist(const float4* __restrict__ in4, long n4,
                         const float* __restrict__ in, long n,
                         const unsigned* __restrict__ mm,
                         unsigned* __restrict__ hist) {
    __shared__ unsigned lh[NBINS * NCOPY];
    for (int i = threadIdx.x; i < NBINS * NCOPY; i += blockDim.x) lh[i] = 0u;
    __syncthreads();
    float tmin = dec_f(mm[0]);
    float tmax = dec_f(mm[1]);
    float scale = (float)NBINS / (tmax - tmin);
    int copy = threadIdx.x & (NCOPY - 1);
    long tid = (long)blockIdx.x * blockDim.x + threadIdx.x;
    long stride = (long)gridDim.x * blockDim.x;

    #define HIST1(v)  do { \
        int ix = (int)(((v) - tmin) * scale); \
        ix = ix < 0 ? 0 : (ix > NBINS - 1 ? NBINS - 1 : ix); \
        atomicAdd(&lh[ix * NCOPY + copy], 1u); } while (0)
    #define HIST4(q)  do { HIST1((q).x); HIST1((q).y); HIST1((q).z); HIST1((q).w); } while (0)

    long i = tid;
    for (; i + 3 * stride < n4; i += 4 * stride) {
        float4 a = in4[i];
        float4 b = in4[i + stride];
        float4 c = in4[i + 2 * stride];
        float4 d = in4[i + 3 * stride];
        HIST4(a); HIST4(b); HIST4(c); HIST4(d);
    }
    for (; i < n4; i += stride) {
        float4 a = in4[i];
        HIST4(a);
    }
    for (long j = n4 * 4 + tid; j < n; j += stride)
        HIST1(in[j]);

    #undef HIST1
    #undef HIST4
    __syncthreads();
    int lane = threadIdx.x & 63;
    for (int b = threadIdx.x; b < NBINS; b += blockDim.x) {
        unsigned t = 0;
        #pragma unroll
        for (int c = 0; c < NCOPY; ++c) {
            int cc = (c + lane) & (NCOPY - 1);
            t += lh[b * NCOPY + cc];
        }
        if (t) atomicAdd(&hist[b], t);
    }
}

__global__ void hrt_fin(const unsigned* __restrict__ hist,
                        const unsigned* __restrict__ mm,
                        float* __restrict__ out) {
    if (threadIdx.x != 0 || blockIdx.x != 0) return;
    float tmin = dec_f(mm[0]);
    float tmax = dec_f(mm[1]);
    float total = 0.0f;
    for (int i = 0; i < NBINS; ++i) total += (float)hist[i];
    float tl = total * (1.0f - 0.99f) / 2.0f;
    float tu = total * (1.0f + 0.99f) / 2.0f;
    int lower = -1, upper = -1;
    float cum = 0.0f;
    for (int i = 0; i < NBINS; ++i) {
        cum += (float)hist[i];
        if (lower < 0 && cum > tl) lower = i;
        if (upper < 0 && cum > tu) upper = i;
    }
    if (lower < 0) lower = 0;
    if (upper < 0) upper = 0;
    float step = (tmax - tmin) / (float)NBINS;
    out[0] = tmin + step * (float)lower;
    out[1] = tmin + step * (float)upper;
}

extern "C" void kernel_launch(void* const* d_in, const int* in_sizes, int n_in,
                              void* d_out, int out_size, void* d_ws, size_t ws_size,
                              hipStream_t stream) {
    const float* in = (const float*)d_in[0];
    long n = (long)in_sizes[0];
    long n4 = n / 4;
    unsigned* ws = (unsigned*)d_ws;
    float* out = (float*)d_out;

    unsigned* pmin = ws;
    unsigned* pmax = ws + GRID1;
    unsigned* hist = ws + 2 * GRID1;
    unsigned* mm   = ws + 2 * GRID1 + NBINS;

    hrt_pass1<<<GRID1, TPB, 0, stream>>>((const float4*)in, n4, in, n,
                                         pmin, pmax, hist);
    hrt_mid<<<1, 512, 0, stream>>>(pmin, pmax, mm);
    hrt_hist<<<GRID2, TPB, 0, stream>>>((const float4*)in, n4, in, n, mm, hist);
    hrt_fin<<<1, 1, 0, stream>>>(hist, mm, out);
}

// Round 10
// 111.788 us; speedup vs baseline: 2.7961x; 1.1609x over previous
//
#include <hip/hip_runtime.h>

#define NBINS 256
#define NCOPY 32
#define GRID1 2048
#define TPB   256
// hist geometry: 512 thr x 1024 blocks = 4 blocks/CU (32 KiB LDS each),
// 32 waves/CU theoretical occupancy, no residency tail.
#define HTPB  512
#define GRID2 1024

// Order-preserving float->uint encoding (monotone increasing).
__device__ __forceinline__ unsigned enc_f(float f) {
    unsigned u = __float_as_uint(f);
    return (u & 0x80000000u) ? ~u : (u | 0x80000000u);
}
__device__ __forceinline__ float dec_f(unsigned u) {
    unsigned v = (u & 0x80000000u) ? (u & 0x7FFFFFFFu) : ~u;
    return __uint_as_float(v);
}

// ws layout (uint32):
//   [0 .. GRID1)                 per-block min (enc), plain-stored every call
//   [GRID1 .. 2*GRID1)           per-block max (enc)
//   [2*GRID1 .. 2*GRID1+NBINS)   global hist bins (zeroed by pass1 block 0)
//   [2*GRID1+NBINS .. +2]        encoded global {min,max} (written by hrt_mid)

__device__ __forceinline__ void minmax16(const float4& a, const float4& b,
                                         const float4& c, const float4& d,
                                         float& lmin, float& lmax) {
    float mn = fminf(fminf(fminf(a.x, a.y), fminf(a.z, a.w)),
                     fminf(fminf(b.x, b.y), fminf(b.z, b.w)));
    mn = fminf(mn, fminf(fminf(fminf(c.x, c.y), fminf(c.z, c.w)),
                         fminf(fminf(d.x, d.y), fminf(d.z, d.w))));
    float mx = fmaxf(fmaxf(fmaxf(a.x, a.y), fmaxf(a.z, a.w)),
                     fmaxf(fmaxf(b.x, b.y), fmaxf(b.z, b.w)));
    mx = fmaxf(mx, fmaxf(fmaxf(fmaxf(c.x, c.y), fmaxf(c.z, c.w)),
                         fmaxf(fmaxf(d.x, d.y), fmaxf(d.z, d.w))));
    lmin = fminf(lmin, mn);
    lmax = fmaxf(lmax, mx);
}

__global__ __launch_bounds__(TPB) void hrt_pass1(
        const float4* __restrict__ in4, long n4,
        const float* __restrict__ in, long n,
        unsigned* __restrict__ pmin, unsigned* __restrict__ pmax,
        unsigned* __restrict__ hist) {
    const int tid = threadIdx.x;
    const int bid = blockIdx.x;

    // block 0 re-inits bins for this call (LLC-homed atomics; ordered vs
    // hist's atomicAdds by the kernel boundary)
    if (bid == 0) {
        for (int j = tid; j < NBINS; j += TPB) atomicExch(&hist[j], 0u);
    }

    float lmin = INFINITY, lmax = -INFINITY;
    const long stride = (long)GRID1 * TPB;
    long i = (long)bid * TPB + tid;
    for (; i + 3 * stride < n4; i += 4 * stride) {
        float4 a = in4[i];
        float4 b = in4[i + stride];
        float4 c = in4[i + 2 * stride];
        float4 d = in4[i + 3 * stride];
        minmax16(a, b, c, d, lmin, lmax);
    }
    for (; i < n4; i += stride) {
        float4 a = in4[i];
        lmin = fminf(lmin, fminf(fminf(a.x, a.y), fminf(a.z, a.w)));
        lmax = fmaxf(lmax, fmaxf(fmaxf(a.x, a.y), fmaxf(a.z, a.w)));
    }
    for (long j = n4 * 4 + (long)bid * TPB + tid; j < n; j += stride) {
        float v = in[j];
        lmin = fminf(lmin, v);
        lmax = fmaxf(lmax, v);
    }

    unsigned emin = enc_f(lmin), emax = enc_f(lmax);
    #pragma unroll
    for (int off = 32; off > 0; off >>= 1) {
        emin = min(emin, (unsigned)__shfl_down((int)emin, off));
        emax = max(emax, (unsigned)__shfl_down((int)emax, off));
    }
    __shared__ unsigned sred[8];
    const int wave = tid >> 6, lane = tid & 63;
    if (lane == 0) { sred[wave] = emin; sred[4 + wave] = emax; }
    __syncthreads();
    if (tid == 0) {
        unsigned m0 = min(min(sred[0], sred[1]), min(sred[2], sred[3]));
        unsigned m1 = max(max(sred[4], sred[5]), max(sred[6], sred[7]));
        pmin[bid] = m0;   // plain stores; kernel boundary publishes them
        pmax[bid] = m1;
    }
}

// Single block: reduce the 2*GRID1 partials once; publish enc'd tmin/tmax.
__global__ void hrt_mid(const unsigned* __restrict__ pmin,
                        const unsigned* __restrict__ pmax,
                        unsigned* __restrict__ mm) {
    __shared__ unsigned sred[16];
    const int tid = threadIdx.x;           // 512 threads
    const int wave = tid >> 6, lane = tid & 63;
    uint4 a = ((const uint4*)pmin)[tid];   // 512 x 4 = 2048 words
    uint4 b = ((const uint4*)pmax)[tid];
    unsigned gmin = min(min(a.x, a.y), min(a.z, a.w));
    unsigned gmax = max(max(b.x, b.y), max(b.z, b.w));
    #pragma unroll
    for (int off = 32; off > 0; off >>= 1) {
        gmin = min(gmin, (unsigned)__shfl_down((int)gmin, off));
        gmax = max(gmax, (unsigned)__shfl_down((int)gmax, off));
    }
    if (lane == 0) { sred[wave] = gmin; sred[8 + wave] = gmax; }
    __syncthreads();
    if (tid == 0) {
        unsigned m0 = sred[0], m1 = sred[8];
        #pragma unroll
        for (int w = 1; w < 8; ++w) {
            m0 = min(m0, sred[w]);
            m1 = max(m1, sred[8 + w]);
        }
        mm[0] = m0;   // plain stores; kernel boundary publishes them
        mm[1] = m1;
    }
}

// Histogram kernel: round-9 inner loop, 512-thread blocks for 32 waves/CU.
__global__ __launch_bounds__(HTPB) void hrt_hist(
        const float4* __restrict__ in4, long n4,
        const float* __restrict__ in, long n,
        const unsigned* __restrict__ mm,
        unsigned* __restrict__ hist) {
    __shared__ unsigned lh[NBINS * NCOPY];
    for (int i = threadIdx.x; i < NBINS * NCOPY; i += HTPB) lh[i] = 0u;
    __syncthreads();
    const float tmin = dec_f(mm[0]);
    const float tmax = dec_f(mm[1]);
    const float scale = (float)NBINS / (tmax - tmin);
    const float bias = -tmin * scale;
    const int copy = threadIdx.x & (NCOPY - 1);
    const long tid = (long)blockIdx.x * HTPB + threadIdx.x;
    const long stride = (long)GRID2 * HTPB;

    #define HIST1(v)  do { \
        int ix = (int)fmaf((v), scale, bias); \
        ix = ix < 0 ? 0 : (ix > NBINS - 1 ? NBINS - 1 : ix); \
        atomicAdd(&lh[ix * NCOPY + copy], 1u); } while (0)
    #define HIST4(q)  do { HIST1((q).x); HIST1((q).y); HIST1((q).z); HIST1((q).w); } while (0)

    long i = tid;
    for (; i + 3 * stride < n4; i += 4 * stride) {
        float4 a = in4[i];
        float4 b = in4[i + stride];
        float4 c = in4[i + 2 * stride];
        float4 d = in4[i + 3 * stride];
        HIST4(a); HIST4(b); HIST4(c); HIST4(d);
    }
    for (; i < n4; i += stride) {
        float4 a = in4[i];
        HIST4(a);
    }
    for (long j = n4 * 4 + tid; j < n; j += stride)
        HIST1(in[j]);

    #undef HIST1
    #undef HIST4
    __syncthreads();
    const int lane = threadIdx.x & 63;
    for (int b = threadIdx.x; b < NBINS; b += HTPB) {
        unsigned t = 0;
        #pragma unroll
        for (int c = 0; c < NCOPY; ++c) {
            int cc = (c + lane) & (NCOPY - 1);
            t += lh[b * NCOPY + cc];
        }
        if (t) atomicAdd(&hist[b], t);
    }
}

__global__ void hrt_fin(const unsigned* __restrict__ hist,
                        const unsigned* __restrict__ mm,
                        float* __restrict__ out) {
    if (threadIdx.x != 0 || blockIdx.x != 0) return;
    float tmin = dec_f(mm[0]);
    float tmax = dec_f(mm[1]);
    float total = 0.0f;
    for (int i = 0; i < NBINS; ++i) total += (float)hist[i];
    float tl = total * (1.0f - 0.99f) / 2.0f;
    float tu = total * (1.0f + 0.99f) / 2.0f;
    int lower = -1, upper = -1;
    float cum = 0.0f;
    for (int i = 0; i < NBINS; ++i) {
        cum += (float)hist[i];
        if (lower < 0 && cum > tl) lower = i;
        if (upper < 0 && cum > tu) upper = i;
    }
    if (lower < 0) lower = 0;
    if (upper < 0) upper = 0;
    float step = (tmax - tmin) / (float)NBINS;
    out[0] = tmin + step * (float)lower;
    out[1] = tmin + step * (float)upper;
}

extern "C" void kernel_launch(void* const* d_in, const int* in_sizes, int n_in,
                              void* d_out, int out_size, void* d_ws, size_t ws_size,
                              hipStream_t stream) {
    const float* in = (const float*)d_in[0];
    long n = (long)in_sizes[0];
    long n4 = n / 4;
    unsigned* ws = (unsigned*)d_ws;
    float* out = (float*)d_out;

    unsigned* pmin = ws;
    unsigned* pmax = ws + GRID1;
    unsigned* hist = ws + 2 * GRID1;
    unsigned* mm   = ws + 2 * GRID1 + NBINS;

    hrt_pass1<<<GRID1, TPB, 0, stream>>>((const float4*)in, n4, in, n,
                                         pmin, pmax, hist);
    hrt_mid<<<1, 512, 0, stream>>>(pmin, pmax, mm);
    hrt_hist<<<GRID2, HTPB, 0, stream>>>((const float4*)in, n4, in, n, mm, hist);
    hrt_fin<<<1, 1, 0, stream>>>(hist, mm, out);
}